// Round 1
// 382.469 us; speedup vs baseline: 1.0132x; 1.0132x over previous
//
#include <hip/hip_runtime.h>

// Problem constants
#define H_DIM 2048
#define E_DIM 8
#define T_DIM 2048
#define F_DIM 4096                 // INTER*2
#define NBLK  1024                 // 8 e * 128 h-chunks; exactly 4 blocks/CU, uniform work
#define HCHUNK 16                  // h-columns per block (one 64B line per t)

typedef float f32x4 __attribute__((ext_vector_type(4)));

// One fused kernel, zero workspace:
//   result = sum_{e,h} A[e,h] * B[e,h],  A = sum_t mask[e,t]*hidden[t,h],  B = sum_f W[e,h,f]
// Block b owns expert e = b>>7 and h-range [h0, h0+16). It computes its own 16 A
// values (phase A, ~128KB/block through L2/L3) then streams its 256KB slice of W
// (phase B, the HBM-bound bulk) and contributes one atomicAdd.
__global__ __launch_bounds__(256, 4) void moe_dot(
    const float* __restrict__ hidden,   // [T, H]
    const float* __restrict__ W,        // [E, H, F]
    const float* __restrict__ mask,     // [E, T]
    float* __restrict__ out) {
  const int tid = threadIdx.x;
  const int bid = blockIdx.x;
  const int e   = bid >> 7;                 // 0..7
  const int h0  = (bid & 127) * HCHUNK;     // 0..2032

  __shared__ float m_lds[T_DIM];            // 8 KB: mask row for this expert
  __shared__ f32x4 redA[4][4];              // cross-wave A reduction
  __shared__ float A_val[HCHUNK];           // A[e, h0+i]
  __shared__ float wsum[4];

  // ---- stage mask[e, :] into LDS (coalesced f32x4) ----
  {
    const f32x4* m4 = (const f32x4*)(mask + (size_t)e * T_DIM);
    f32x4* l4 = (f32x4*)m_lds;
    l4[tid]       = m4[tid];
    l4[tid + 256] = m4[tid + 256];
  }
  __syncthreads();

  // ---- phase A: A[e, h0+hh] = sum_t mask[e,t] * hidden[t, h0+hh] ----
  // thread = (ttg, hq): hq = tid&3 owns h-quad h0+4*hq..+3 (16B f32x4),
  // ttg = tid>>2 in 0..63 strides t. Wave reads 16 full 64B lines per instr.
  {
    const int hq  = tid & 3;
    const int ttg = tid >> 2;                 // 0..63
    const float* hp = hidden + h0 + (hq << 2);
    f32x4 acc = (f32x4)0.f;
    #pragma unroll 8
    for (int k = 0; k < 32; ++k) {
      int t = ttg + (k << 6);
      f32x4 hv = *(const f32x4*)(hp + (size_t)t * H_DIM);
      acc += hv * m_lds[t];                   // 4-lane-uniform LDS broadcast
    }
    // reduce over ttg within wave (offsets 4,8,16,32), per component
    #pragma unroll
    for (int off = 4; off <= 32; off <<= 1) {
      acc.x += __shfl_down(acc.x, off, 64);
      acc.y += __shfl_down(acc.y, off, 64);
      acc.z += __shfl_down(acc.z, off, 64);
      acc.w += __shfl_down(acc.w, off, 64);
    }
    const int wave = tid >> 6;
    const int lane = tid & 63;
    if (lane < 4) redA[wave][lane] = acc;
    __syncthreads();
    if (tid < 4) {
      f32x4 a = redA[0][tid] + redA[1][tid] + redA[2][tid] + redA[3][tid];
      ((f32x4*)A_val)[tid] = a;
    }
    __syncthreads();
  }

  // ---- phase B: stream W rows, dot with A ----
  // wave w owns 4 contiguous rows h = h0 + 4w + j  (64 KB contiguous per wave)
  const int wave = tid >> 6;
  const int lane = tid & 63;
  const int rl   = wave << 2;
  const f32x4* rp = (const f32x4*)(W + ((size_t)e * H_DIM + h0 + rl) * F_DIM);

  f32x4 a0 = (f32x4)0.f, a1 = (f32x4)0.f, a2 = (f32x4)0.f, a3 = (f32x4)0.f;
  #pragma unroll
  for (int i = 0; i < 16; ++i) {            // 16 x 1KB coalesced, independent
    int idx = lane + (i << 6);
    a0 += rp[idx];
    a1 += rp[idx + 1024];                   // +1 row (4096 floats)
    a2 += rp[idx + 2048];
    a3 += rp[idx + 3072];
  }
  float dot = ((a0.x + a0.y) + (a0.z + a0.w)) * A_val[rl]
            + ((a1.x + a1.y) + (a1.z + a1.w)) * A_val[rl + 1]
            + ((a2.x + a2.y) + (a2.z + a2.w)) * A_val[rl + 2]
            + ((a3.x + a3.y) + (a3.z + a3.w)) * A_val[rl + 3];

  #pragma unroll
  for (int off = 32; off > 0; off >>= 1)
    dot += __shfl_down(dot, off, 64);
  if (lane == 0) wsum[wave] = dot;
  __syncthreads();
  if (tid == 0)
    atomicAdd(out, (wsum[0] + wsum[1]) + (wsum[2] + wsum[3]));
}

extern "C" void kernel_launch(void* const* d_in, const int* in_sizes, int n_in,
                              void* d_out, int out_size, void* d_ws, size_t ws_size,
                              hipStream_t stream) {
  const float* hidden = (const float*)d_in[0];  // [1,1,T,H] fp32
  const float* W      = (const float*)d_in[1];  // [1,E,H,2*INTER] fp32
  const float* mask   = (const float*)d_in[2];  // [1,E,T,1] fp32
  float* out = (float*)d_out;

  hipMemsetAsync(d_out, 0, sizeof(float), stream);   // graph-capturable memset node
  moe_dot<<<NBLK, 256, 0, stream>>>(hidden, W, mask, out);
}